// Round 5
// baseline (84.723 us; speedup 1.0000x reference)
//
#include <hip/hip_runtime.h>
#include <math.h>

#define NROWS 2048
#define MCOLS 32

// Taylor erf on |x| <= 1/(2*sqrt(2)): erf(x) = c1 x + c3 x^3 + c5 x^5 + c7 x^7
#define C1 1.1283791671f
#define C3 (-0.3761263890f)
#define C5 0.1128379167f
#define C7 (-0.0268661706f)

// Kernel A: 64 blocks x 256 threads. Block b covers rows b*32..b*32+31 (1024 elems).
// float4 loads; t=exp(expr-tr), e=exp(risk) staged in LDS; thread (q,k) reduces
// moment partial sum_r e*t^q over the block's 32 rows; q==0 threads also track
// the column max. No atomics: partials -> ws_partial[b][256], max -> ws_pmax[b][32].
__global__ __launch_bounds__(256) void k_moments(const float4* __restrict__ expr4,
                                                 const float4* __restrict__ tr4,
                                                 const float4* __restrict__ risk4,
                                                 float* __restrict__ partial,
                                                 float* __restrict__ pmax,
                                                 float* __restrict__ out) {
    int tid = threadIdx.x, b = blockIdx.x;
    int i4 = b * 256 + tid;              // float4 index; elems i4*4 .. i4*4+3

    float4 ex = expr4[i4];
    float4 tv = tr4[i4];
    float4 rk = risk4[i4];

    __shared__ float sm_t[1024];
    __shared__ float sm_e[1024];
    float4 t4 = make_float4(__expf(ex.x - tv.x), __expf(ex.y - tv.y),
                            __expf(ex.z - tv.z), __expf(ex.w - tv.w));
    float4 e4 = make_float4(__expf(rk.x), __expf(rk.y),
                            __expf(rk.z), __expf(rk.w));
    ((float4*)sm_t)[tid] = t4;
    ((float4*)sm_e)[tid] = e4;
    __syncthreads();

    int q = tid >> 5;                    // 0..7
    int k = tid & 31;
    float part = 0.0f, mx = 0.0f;
#pragma unroll
    for (int r = 0; r < 32; r++) {
        float t = sm_t[r * 32 + k];
        float e = sm_e[r * 32 + k];
        float p = e;
#pragma unroll 7
        for (int m = 0; m < q; m++) p *= t;   // e * t^q (q wave-pair-uniform)
        part += p;
        mx = fmaxf(mx, t);
    }
    partial[b * 256 + tid] = part;
    if (q == 0) pmax[b * 32 + k] = mx;
    if (b == 0 && tid == 0) out[0] = 0.0f;
}

// Kernel B: 64 blocks x 256 threads. Prologue: reduce the 64 moment partials and
// column maxes (redundantly per block, L2-resident), 32 threads build the Horner
// coefficients D_0..7 per column. Main: recompute t,e from inputs, Horner + log,
// block reduce, one atomicAdd per block.
__global__ __launch_bounds__(256) void k_loss(const float4* __restrict__ expr4,
                                              const float4* __restrict__ tr4,
                                              const float4* __restrict__ risk4,
                                              const float4* __restrict__ event4,
                                              const float* __restrict__ sigma,
                                              const float* __restrict__ partial,
                                              const float* __restrict__ pmax,
                                              float* __restrict__ out) {
    int tid = threadIdx.x;
    __shared__ float sM[256];
    __shared__ float sMax[32];
    __shared__ float sD[256];
    __shared__ float sSc[32];
    __shared__ float sSh[32];
    __shared__ float warpsum[4];

    // reduce moment partials over 64 blocks
    float acc = 0.0f;
    for (int bb = 0; bb < 64; bb++) acc += partial[bb * 256 + tid];
    sM[tid] = acc;
    if (tid < 32) {
        float mx = 0.0f;
        for (int bb = 0; bb < 64; bb++) mx = fmaxf(mx, pmax[bb * 32 + tid]);
        sMax[tid] = mx;
    }
    __syncthreads();

    if (tid < 32) {
        int k = tid;
        float s = 1.0f / (sMax[k] * 2.0f * sigma[0] * sqrtf(2.0f));
        float M[8];
        float sp = 1.0f;
#pragma unroll
        for (int q = 0; q < 8; q++) { M[q] = sM[q * 32 + k] * sp; sp *= s; }
        sD[0 * 32 + k] = C1 * M[1] +         C3 * M[3] +         C5 * M[5] +        C7 * M[7];
        sD[1 * 32 + k] = C1 * M[0] + 3.0f *  C3 * M[2] + 5.0f *  C5 * M[4] + 7.0f * C7 * M[6];
        sD[2 * 32 + k] = 3.0f * C3 * M[1] + 10.0f * C5 * M[3] + 21.0f * C7 * M[5];
        sD[3 * 32 + k] = C3 * M[0] + 10.0f * C5 * M[2] + 35.0f * C7 * M[4];
        sD[4 * 32 + k] = 5.0f * C5 * M[1] + 35.0f * C7 * M[3];
        sD[5 * 32 + k] = C5 * M[0] + 21.0f * C7 * M[2];
        sD[6 * 32 + k] = 7.0f * C7 * M[1];
        sD[7 * 32 + k] = C7 * M[0];
        sSc[k] = s;
        sSh[k] = 0.5f * M[0];
    }
    __syncthreads();

    int i4 = blockIdx.x * 256 + tid;     // same tiling as kernel A
    float4 ex = expr4[i4];
    float4 tv = tr4[i4];
    float4 rk = risk4[i4];
    float4 ev = event4[i4];

    float c = 0.0f;
    const float* exp_ = &ex.x; const float* trp = &tv.x;
    const float* rkp  = &rk.x; const float* evp = &ev.x;
    int k0 = (tid * 4) & 31;
#pragma unroll
    for (int j = 0; j < 4; j++) {
        int k = k0 + j;
        float t = __expf(exp_[j] - trp[j]);
        float e = __expf(rkp[j]);
        float w = -(t * sSc[k]);
        float h = sD[7 * 32 + k];
#pragma unroll
        for (int q = 6; q >= 0; q--) h = fmaf(h, w, sD[q * 32 + k]);
        float cum = sSh[k] + 0.5f * (h + e);
        c += (__logf(cum) - rkp[j]) * evp[j];
    }

    for (int off = 32; off > 0; off >>= 1)
        c += __shfl_down(c, off, 64);
    if ((tid & 63) == 0) warpsum[tid >> 6] = c;
    __syncthreads();
    if (tid == 0) {
        float s = (warpsum[0] + warpsum[1]) + (warpsum[2] + warpsum[3]);
        atomicAdd(out, s);
    }
}

extern "C" void kernel_launch(void* const* d_in, const int* in_sizes, int n_in,
                              void* d_out, int out_size, void* d_ws, size_t ws_size,
                              hipStream_t stream) {
    const float4* risk  = (const float4*)d_in[0];
    const float4* expr  = (const float4*)d_in[1];
    const float4* tr    = (const float4*)d_in[2];
    const float4* event = (const float4*)d_in[3];
    const float*  sigma = (const float*)d_in[4];
    float* out = (float*)d_out;

    float* ws_partial = (float*)d_ws;            // 64 * 256
    float* ws_pmax    = ws_partial + 64 * 256;   // 64 * 32

    k_moments<<<64, 256, 0, stream>>>(expr, tr, risk, ws_partial, ws_pmax, out);
    k_loss<<<64, 256, 0, stream>>>(expr, tr, risk, event, sigma,
                                   ws_partial, ws_pmax, out);
}